// Round 5
// baseline (152.786 us; speedup 1.0000x reference)
//
#include <hip/hip_runtime.h>
#include <stdint.h>
#include <math.h>

typedef unsigned int u32;
typedef unsigned long long u64;

#define NN_ 28800
#define MM_ 64
#define BB_ 16
#define XROW_ 25
#define POS_CAP_ 128u
#define BATCH_ 256u

struct Keys { u32 k[BB_][4]; };

// ---------------- threefry2x32 (JAX-exact), host+device ----------------
__host__ __device__ __forceinline__ u32 rotl32(u32 v, u32 r){ return (v<<r)|(v>>(32u-r)); }

__host__ __device__ __forceinline__ void tf2x32(u32 k0, u32 k1, u32 x0, u32 x1, u32& y0, u32& y1){
  u32 ks2 = k0 ^ k1 ^ 0x1BD11BDAu;
  x0 += k0; x1 += k1;
#define TFR(r) { x0 += x1; x1 = rotl32(x1,(r)); x1 ^= x0; }
  TFR(13) TFR(15) TFR(26) TFR(6)   x0 += k1;  x1 += ks2 + 1u;
  TFR(17) TFR(29) TFR(16) TFR(24)  x0 += ks2; x1 += k0  + 2u;
  TFR(13) TFR(15) TFR(26) TFR(6)   x0 += k0;  x1 += k1  + 3u;
  TFR(17) TFR(29) TFR(16) TFR(24)  x0 += k1;  x1 += ks2 + 4u;
  TFR(13) TFR(15) TFR(26) TFR(6)   x0 += ks2; x1 += k0  + 5u;
#undef TFR
  y0 = x0; y1 = x1;
}

// ---------------- anchors: pure-float, bit-exact vs numpy ----------------
__device__ __forceinline__ void anchor_from(int a, int cell,
                                            float& ox1, float& oy1, float& ox2, float& oy2){
  #pragma clang fp contract(off)
  int w = cell & 63;
  int h = cell >> 6;
  int p = (a >= 6) ? 2 : ((a >= 3) ? 1 : 0);
  int q = a - p*3;
  float sf = (p==0) ? 128.0f : ((p==1) ? 256.0f : 512.0f);
  const float SQH = 0.70710678118654752440f;
  const float SQ2 = 1.41421356237309514547f;
  float cw = (q==0) ? SQH : ((q==1) ? 1.0f : SQ2);
  float ch = (q==0) ? SQ2 : ((q==1) ? 1.0f : SQH);
  float hx = (sf*cw) * 0.5f;
  float hy = (sf*ch) * 0.5f;
  float cx = ((float)w + 0.5f) * 16.0f;
  float cy = ((float)h + 0.5f) * 16.0f;
  float X1 = (cx - hx) / 1024.0f;
  float Y1 = (cy - hy) / 800.0f;
  float X2 = (cx + hx) / 1024.0f;
  float Y2 = (cy + hy) / 800.0f;
  bool valid = (X1 > 0.0f) && (Y1 > 0.0f) && (X2 < 1.0f) && (Y2 < 1.0f);
  ox1 = valid ? X1 : 0.0f;
  oy1 = valid ? Y1 : 0.0f;
  ox2 = valid ? X2 : 0.0f;
  oy2 = valid ? Y2 : 0.0f;
}

// ---------------- K1 fused: IoU + per-gt argmax (shfl) + threefry + hist/counts ----------------
__global__ __launch_bounds__(128, 6) void k_main(const float* __restrict__ x, Keys keys,
                                                 unsigned char* __restrict__ midx,
                                                 u64* __restrict__ bestkey,
                                                 u32* __restrict__ rpv, u32* __restrict__ rnv,
                                                 u32* __restrict__ counts, u32* __restrict__ hist){
  #pragma clang fp contract(off)
  int tid = threadIdx.x;          // 0..127 (2 waves)
  int lane = tid & 63;
  int b = blockIdx.y;
  int i = blockIdx.x*128 + tid;   // anchor index, always < NN_ (225*128 = 28800)

  __shared__ float4 g4[MM_];
  __shared__ float  ga[MM_];
  if (tid < MM_){
    const float* gp = x + (b*MM_ + tid)*XROW_ + 21;
    float g0 = gp[0], g1 = gp[1], g2 = gp[2], g3 = gp[3];
    g4[tid] = make_float4(g0,g1,g2,g3);
    ga[tid] = (g2-g0)*(g3-g1);    // exact reference op order
  }
  __syncthreads();

  int a = i % 9, cell = i / 9;
  float ax1,ay1,ax2,ay2;
  anchor_from(a, cell, ax1,ay1,ax2,ay2);
  float area_a = (ax2-ax1)*(ay2-ay1);

  float best = -1.0f; int bj = 0;
  bool av = (ax2 > 0.0f);
  if (__ballot(av) != 0ull){      // wave-level skip for fully-invalid waves
    for (int j = 0; j < MM_; ++j){
      float4 gg = g4[j];
      float ix1 = fmaxf(ax1,gg.x), iy1 = fmaxf(ay1,gg.y);
      float ix2 = fminf(ax2,gg.z), iy2 = fminf(ay2,gg.w);
      float iw = fmaxf(ix2-ix1, 0.0f), ih = fmaxf(iy2-iy1, 0.0f);
      float inter = iw*ih;
      float den = area_a + ga[j];   // exact reference op order, no FMA
      den = den - inter;
      den = den + 1e-7f;
      float iou = inter / den;
      if (iou > best){ best = iou; bj = j; }   // first-max semantics
      // per-gt wave max: 6-step butterfly on iou bits (iou >= 0, order-isomorphic)
      u32 ib = __float_as_uint(iou);
      u32 mx = ib;
      mx = max(mx, (u32)__shfl_xor((int)mx,  1, 64));
      mx = max(mx, (u32)__shfl_xor((int)mx,  2, 64));
      mx = max(mx, (u32)__shfl_xor((int)mx,  4, 64));
      mx = max(mx, (u32)__shfl_xor((int)mx,  8, 64));
      mx = max(mx, (u32)__shfl_xor((int)mx, 16, 64));
      mx = max(mx, (u32)__shfl_xor((int)mx, 32, 64));
      if (mx){
        u64 who = __ballot(ib == mx);
        if (lane == __ffsll((unsigned long long)who) - 1)   // lowest lane = smallest i
          atomicMax(&bestkey[b*MM_ + j], ((u64)mx << 32) | (u64)(0xFFFFFFFFu - (u32)i));
      }
    }
  } else {
    best = 0.0f;                  // all-invalid: iou==0 for every gt, argmax=0
  }

  // threefry draws + candidate ranks + hist/counts (was k_rand)
  u32 a0,a1,c0,c1;
  tf2x32(keys.k[b][0], keys.k[b][1], 0u, (u32)i, a0,a1);
  tf2x32(keys.k[b][2], keys.k[b][3], 0u, (u32)i, c0,c1);
  u32 ph = (a0^a1) >> 9, nh = (c0^c1) >> 9;   // 23-bit rank keys
  bool pc = (best > 0.7f);
  bool nc = (best < 0.3f);
  rpv[b*NN_+i] = pc ? ph + 1u : 0u;
  rnv[b*NN_+i] = nc ? nh + 1u : 0u;
  midx[b*NN_+i] = (unsigned char)bj;
  if (pc) atomicAdd(&hist[((b*2+0)<<12) + (ph>>11)], 1u);
  if (nc) atomicAdd(&hist[((b*2+1)<<12) + (nh>>11)], 1u);
  u64 bp = __ballot(pc), bn = __ballot(nc);
  if (lane == 0){
    if (bp) atomicAdd(&counts[b*2+0], (u32)__popcll(bp));
    if (bn) atomicAdd(&counts[b*2+1], (u32)__popcll(bn));
  }
}

// ---------------- K2: forced-anchor fixup (dedup via atomicExch) ----------------
__global__ __launch_bounds__(64) void k_fix(const u64* __restrict__ bestkey, Keys keys,
                                            u32* __restrict__ rpv,
                                            u32* __restrict__ counts, u32* __restrict__ hist){
  int b = blockIdx.x, j = threadIdx.x;
  u64 key = bestkey[b*MM_ + j];
  bool add = false;
  if ((u32)(key >> 32) != 0u){    // best_iou > 0
    u32 ist = 0xFFFFFFFFu - (u32)key;
    u32 a0,a1;
    tf2x32(keys.k[b][0], keys.k[b][1], 0u, ist, a0,a1);
    u32 ph = (a0^a1) >> 9;
    u32 old = atomicExch(&rpv[b*NN_ + ist], ph + 1u);   // same value regardless of writer
    if (old == 0u){
      add = true;
      atomicAdd(&hist[((b*2+0)<<12) + (ph>>11)], 1u);
    }
  }
  u64 bal = __ballot(add);
  if (j == 0 && bal) atomicAdd(&counts[b*2+0], (u32)__popcll(bal));
}

// ---------------- K3: threshold bin + collect + exact (vstar,cut), one block per (b,cls) ----------------
__global__ __launch_bounds__(256) void k_sel(const u32* __restrict__ rpv,
                                             const u32* __restrict__ rnv,
                                             const u32* __restrict__ counts,
                                             const u32* __restrict__ hist,
                                             u32* __restrict__ selp){
  int cls = blockIdx.x, b = blockIdx.y, tid = threadIdx.x;
  int id = b*2 + cls;
  u32 posc = counts[b*2+0], negc = counts[b*2+1];
  u32 npos = min(posc, POS_CAP_);
  u32 K   = cls ? (BATCH_ - npos) : npos;
  u32 cnt = cls ? negc : posc;
  if (cnt <= K){
    if (tid == 0){ selp[id*2+0] = 0u; selp[id*2+1] = 0xFFFFFFFFu; }
    return;
  }
  const u32* H = hist + (id << 12);
  __shared__ u32 ts[256], ss[256];
  __shared__ u32 bc[2];
  u32 s = 0;
  #pragma unroll
  for (int q = 0; q < 16; ++q) s += H[tid*16 + q];
  ts[tid] = s; ss[tid] = s;
  __syncthreads();
  for (int off = 1; off < 256; off <<= 1){
    u32 vv = (tid + off < 256) ? ss[tid + off] : 0u;
    __syncthreads();
    ss[tid] += vv;
    __syncthreads();
  }
  u32 excl = (tid < 255) ? ss[tid+1] : 0u;
  if (excl < K && excl + ts[tid] >= K){
    u32 acc = excl;
    for (int q = 15; q >= 0; --q){
      u32 h = H[tid*16 + q];
      if (acc + h >= K){ bc[0] = (u32)(tid*16 + q); bc[1] = K - acc; break; }
      acc += h;
    }
  }
  __syncthreads();
  u32 B = bc[0], Kp = bc[1];
  const u32* v = (cls ? rnv : rpv) + (size_t)b*NN_;
  __shared__ u64 L[512];
  __shared__ u32 lc;
  if (tid == 0) lc = 0;
  __syncthreads();
  for (int i2 = tid; i2 < NN_; i2 += 256){
    u32 xv = v[i2];
    if (xv && ((xv - 1u) >> 11) == B){
      u32 p = atomicAdd(&lc, 1u);
      if (p < 512u) L[p] = ((u64)xv << 32) | (u32)i2;
    }
  }
  __syncthreads();
  u32 n = min(lc, 512u);
  for (u32 e = tid; e < n; e += 256){
    u64 me = L[e]; u32 mv = (u32)(me >> 32), mi = (u32)me;
    u32 r = 0;
    for (u32 t2 = 0; t2 < n; ++t2){
      u64 o = L[t2]; u32 ov = (u32)(o >> 32), oi = (u32)o;
      r += (ov > mv) || (ov == mv && oi < mi);
    }
    if (r == Kp - 1u){ selp[id*2+0] = mv; selp[id*2+1] = mi; }
  }
}

// ---------------- K4: final cls + encoded offsets ----------------
__global__ __launch_bounds__(256) void k_out(const float* __restrict__ x,
                                             const unsigned char* __restrict__ midx,
                                             const u32* __restrict__ rpv,
                                             const u32* __restrict__ rnv,
                                             const u32* __restrict__ selp,
                                             float* __restrict__ out){
  #pragma clang fp contract(off)
  int b = blockIdx.y, tid = threadIdx.x;
  __shared__ float g[MM_][4];
  g[tid>>2][tid&3] = x[b*MM_*XROW_ + (tid>>2)*XROW_ + 21 + (tid&3)];
  __syncthreads();
  int i = blockIdx.x*256 + tid;
  if (i >= NN_) return;

  u32 pth = selp[(b*2+0)*2+0], pcut = selp[(b*2+0)*2+1];
  u32 nth = selp[(b*2+1)*2+0], ncut = selp[(b*2+1)*2+1];
  u32 pv = rpv[b*NN_+i], nv = rnv[b*NN_+i];
  bool selpos = (pv > 0u) && (pv > pth || (pv == pth && (u32)i <= pcut));
  bool selneg = (nv > 0u) && (nv > nth || (nv == nth && (u32)i <= ncut));
  float cls = selpos ? 1.0f : -1.0f;
  if (selneg) cls = 0.0f;

  float tx = 0.0f, ty = 0.0f, tw = 0.0f, th = 0.0f;
  if (selpos){
    int j = midx[b*NN_+i];
    float g0=g[j][0], g1=g[j][1], g2=g[j][2], g3=g[j][3];
    int a = i % 9, cell = i / 9;
    float ax1,ay1,ax2,ay2;
    anchor_from(a, cell, ax1,ay1,ax2,ay2);
    float wgt = g2-g0, hgt = g3-g1;
    float xcg = (g2+g0)*0.5f, ycg = (g3+g1)*0.5f;
    float wr = ax2-ax1, hr = ay2-ay1;
    float xcr = (ax2+ax1)*0.5f, ycr = (ay2+ay1)*0.5f;
    float wrs = (wr > 0.0f) ? wr : 1.0f;
    float hrs = (hr > 0.0f) ? hr : 1.0f;
    tx = (wgt > 0.0f) ? (xcg - xcr)/wrs : 0.0f;
    ty = (hgt > 0.0f) ? (ycg - ycr)/hrs : 0.0f;
    tw = (wgt > 0.0f) ? logf(wgt/wrs) : 0.0f;
    th = (hgt > 0.0f) ? logf(hgt/hrs) : 0.0f;
  }
  float* o = out + (size_t)(b*NN_+i)*5;
  o[0] = cls; o[1] = tx; o[2] = ty; o[3] = tw; o[4] = th;
}

extern "C" void kernel_launch(void* const* d_in, const int* in_sizes, int n_in,
                              void* d_out, int out_size, void* d_ws, size_t ws_size,
                              hipStream_t stream) {
  const float* x = (const float*)d_in[0];
  float* out = (float*)d_out;
  char* ws = (char*)d_ws;

  // ws layout — zero-span [0, 532736) covers counts+bestkey+hist
  u32* counts  = (u32*)(ws + 0);          // 128 B
  u64* bestkey = (u64*)(ws + 256);        // 8 KiB
  u32* hist    = (u32*)(ws + 8448);       // 512 KiB (2*16*4096*4)
  u32* selp    = (u32*)(ws + 532736);     // 256 B (always fully written by k_sel)
  unsigned char* midx = (unsigned char*)(ws + 532992);   // 450 KiB
  u32* rpv = (u32*)(ws + 993792);         // 1.76 MiB
  u32* rnv = (u32*)(ws + 2836992);        // 1.76 MiB (end ~4.47 MiB)
  (void)ws_size; (void)in_sizes; (void)n_in; (void)out_size;

  // host-side JAX key derivation (partitionable threefry), deterministic
  Keys keys;
  for (int b = 0; b < BB_; ++b){
    u32 r0, r1;
    tf2x32(0u, 42u, 0u, (u32)b, r0, r1);
    tf2x32(r0, r1, 0u, 0u, keys.k[b][0], keys.k[b][1]);
    tf2x32(r0, r1, 0u, 1u, keys.k[b][2], keys.k[b][3]);
  }

  hipMemsetAsync(ws, 0, 532736, stream);
  k_main<<<dim3(225, BB_), 128, 0, stream>>>(x, keys, midx, bestkey, rpv, rnv, counts, hist);
  k_fix <<<dim3(BB_), 64, 0, stream>>>(bestkey, keys, rpv, counts, hist);
  k_sel <<<dim3(2, BB_), 256, 0, stream>>>(rpv, rnv, counts, hist, selp);
  k_out <<<dim3(113, BB_), 256, 0, stream>>>(x, midx, rpv, rnv, selp, out);
}